// Round 1
// baseline (1457.363 us; speedup 1.0000x reference)
//
#include <hip/hip_runtime.h>
#include <math.h>

#define NTOK 49
#define KDIM 128
#define NH 4
#define HD 32
#define QK_SCALE 0.17677669529663687f  // 32^-0.5

// LDS layout (static, total ~158.7 KB -> 1 block/CU):
//   xs   [49][129]  : x tile (padded +1 to kill bank conflicts)
//   wt   [64][129]  : staged weight tile (qkv_w / proj_w), padded
//   s_qt [4][32][49]: q transposed per head (pre-scaled by QK_SCALE)
//   s_k  [4][49][32]
//   s_v  [4][49][32]
//   s_ot [128][49]  : attention output transposed (for proj GEMM)

__launch_bounds__(256, 1)
__global__ void swin_window_attn_kernel(
    const float* __restrict__ x,
    const float* __restrict__ attn_mask,
    const float* __restrict__ qkv_w,
    const float* __restrict__ qkv_b,
    const float* __restrict__ proj_w,
    const float* __restrict__ proj_b,
    const float* __restrict__ bias_table,
    const int*  __restrict__ rel_index,
    float* __restrict__ out)
{
    __shared__ float xs[NTOK * 129];
    __shared__ float wt[64 * 129];
    __shared__ float s_qt[NH * HD * NTOK];
    __shared__ float s_k[NH * NTOK * HD];
    __shared__ float s_v[NH * NTOK * HD];
    __shared__ float s_ot[KDIM * NTOK];

    const int b   = blockIdx.x;
    const int tid = threadIdx.x;
    const int wm  = b & 63;              // mask group = b % NW

    // ---------------- Phase A: load x tile ----------------
    const float* xg = x + (size_t)b * (NTOK * KDIM);
    for (int i = tid; i < (NTOK * KDIM) / 4; i += 256) {
        float4 t = reinterpret_cast<const float4*>(xg)[i];
        int idx = i * 4;
        int row = idx >> 7, col = idx & 127;
        float* dst = &xs[row * 129 + col];
        dst[0] = t.x; dst[1] = t.y; dst[2] = t.z; dst[3] = t.w;
    }
    __syncthreads();

    const int cx = tid & 15;   // 16 column groups of 4
    const int ny = tid >> 4;   // 16 row groups; rows ny, ny+16, ny+32, (ny+48)

    // Clamped row pointers (rows >=49 duplicate row 48; their writes are guarded)
    const float* xrow[4];
    #pragma unroll
    for (int a = 0; a < 4; ++a) {
        int n = ny + 16 * a;
        xrow[a] = &xs[(n < NTOK ? n : NTOK - 1) * 129];
    }

    // ---------------- Phase B: QKV = x @ qkv_w^T + qkv_b ----------------
    for (int ct = 0; ct < 6; ++ct) {
        // stage 64x128 fp32 weight tile
        const float4* wg = reinterpret_cast<const float4*>(qkv_w + ct * (64 * KDIM));
        for (int i = tid; i < (64 * KDIM) / 4; i += 256) {
            float4 t = wg[i];
            int idx = i * 4;
            int row = idx >> 7, col = idx & 127;
            float* dst = &wt[row * 129 + col];
            dst[0] = t.x; dst[1] = t.y; dst[2] = t.z; dst[3] = t.w;
        }
        __syncthreads();

        float acc[4][4];
        #pragma unroll
        for (int a = 0; a < 4; ++a)
            #pragma unroll
            for (int j = 0; j < 4; ++j) acc[a][j] = 0.f;

        for (int k = 0; k < KDIM; ++k) {
            float xr[4], wr[4];
            #pragma unroll
            for (int a = 0; a < 4; ++a) xr[a] = xrow[a][k];
            #pragma unroll
            for (int j = 0; j < 4; ++j) wr[j] = wt[(cx * 4 + j) * 129 + k];
            #pragma unroll
            for (int a = 0; a < 4; ++a)
                #pragma unroll
                for (int j = 0; j < 4; ++j) acc[a][j] += xr[a] * wr[j];
        }

        #pragma unroll
        for (int j = 0; j < 4; ++j) {
            const int c     = ct * 64 + cx * 4 + j;
            const int which = c >> 7;
            const int h     = (c >> 5) & 3;
            const int d     = c & 31;
            const float bv  = qkv_b[c];
            #pragma unroll
            for (int a = 0; a < 4; ++a) {
                int n = ny + 16 * a;
                if (n < NTOK) {
                    float val = acc[a][j] + bv;
                    if (which == 0)      s_qt[(h * HD + d) * NTOK + n] = val * QK_SCALE;
                    else if (which == 1) s_k[(h * NTOK + n) * HD + d] = val;
                    else                 s_v[(h * NTOK + n) * HD + d] = val;
                }
            }
        }
        __syncthreads();
    }

    // ---------------- Phase C: per-head attention (one wave per head) ----------------
    {
        const int h    = tid >> 6;          // wave id = head
        const int lane = tid & 63;
        const int r    = lane < NTOK ? lane : NTOK - 1;

        float qreg[HD];
        #pragma unroll
        for (int d = 0; d < HD; ++d) qreg[d] = s_qt[(h * HD + d) * NTOK + r];

        const int*   ri   = rel_index + r * NTOK;
        const float* mrow = attn_mask + ((size_t)wm * NTOK + r) * NTOK;

        float p[NTOK];
        float mx = -1e30f;
        #pragma unroll
        for (int j = 0; j < NTOK; ++j) {
            const float* krow = &s_k[(h * NTOK + j) * HD];
            float s = 0.f;
            #pragma unroll
            for (int d = 0; d < HD; ++d) s += qreg[d] * krow[d];
            s += bias_table[ri[j] * NH + h] + mrow[j];
            p[j] = s;
            mx = fmaxf(mx, s);
        }
        float sum = 0.f;
        #pragma unroll
        for (int j = 0; j < NTOK; ++j) {
            float e = __expf(p[j] - mx);
            p[j] = e;
            sum += e;
        }
        const float rs = 1.0f / sum;

        float o[HD];
        #pragma unroll
        for (int d = 0; d < HD; ++d) o[d] = 0.f;
        #pragma unroll
        for (int j = 0; j < NTOK; ++j) {
            float pj = p[j] * rs;
            const float* vrow = &s_v[(h * NTOK + j) * HD];
            #pragma unroll
            for (int d = 0; d < HD; ++d) o[d] += pj * vrow[d];
        }
        if (lane < NTOK) {
            #pragma unroll
            for (int d = 0; d < HD; ++d) s_ot[(h * HD + d) * NTOK + r] = o[d];
        }
    }
    __syncthreads();

    // ---------------- Phase D: out = attn_out @ proj_w^T + proj_b ----------------
    float* outg = out + (size_t)b * (NTOK * KDIM);
    for (int ct = 0; ct < 2; ++ct) {
        const float4* wg = reinterpret_cast<const float4*>(proj_w + ct * (64 * KDIM));
        for (int i = tid; i < (64 * KDIM) / 4; i += 256) {
            float4 t = wg[i];
            int idx = i * 4;
            int row = idx >> 7, col = idx & 127;
            float* dst = &wt[row * 129 + col];
            dst[0] = t.x; dst[1] = t.y; dst[2] = t.z; dst[3] = t.w;
        }
        __syncthreads();

        float acc[4][4];
        #pragma unroll
        for (int a = 0; a < 4; ++a)
            #pragma unroll
            for (int j = 0; j < 4; ++j) acc[a][j] = 0.f;

        int nclamp[4];
        #pragma unroll
        for (int a = 0; a < 4; ++a) {
            int n = ny + 16 * a;
            nclamp[a] = (n < NTOK ? n : NTOK - 1);
        }

        for (int k = 0; k < KDIM; ++k) {
            float xr[4], wr[4];
            #pragma unroll
            for (int a = 0; a < 4; ++a) xr[a] = s_ot[k * NTOK + nclamp[a]];
            #pragma unroll
            for (int j = 0; j < 4; ++j) wr[j] = wt[(cx * 4 + j) * 129 + k];
            #pragma unroll
            for (int a = 0; a < 4; ++a)
                #pragma unroll
                for (int j = 0; j < 4; ++j) acc[a][j] += xr[a] * wr[j];
        }

        const int c0 = ct * 64 + cx * 4;
        float pb[4];
        #pragma unroll
        for (int j = 0; j < 4; ++j) pb[j] = proj_b[c0 + j];

        #pragma unroll
        for (int a = 0; a < 4; ++a) {
            int n = ny + 16 * a;
            if (n < NTOK) {
                float4 res;
                res.x = acc[a][0] + pb[0];
                res.y = acc[a][1] + pb[1];
                res.z = acc[a][2] + pb[2];
                res.w = acc[a][3] + pb[3];
                *reinterpret_cast<float4*>(&outg[n * KDIM + c0]) = res;
            }
        }
        __syncthreads();
    }
}

extern "C" void kernel_launch(void* const* d_in, const int* in_sizes, int n_in,
                              void* d_out, int out_size, void* d_ws, size_t ws_size,
                              hipStream_t stream) {
    const float* x          = (const float*)d_in[0];
    const float* attn_mask  = (const float*)d_in[1];
    const float* qkv_w      = (const float*)d_in[2];
    const float* qkv_b      = (const float*)d_in[3];
    const float* proj_w     = (const float*)d_in[4];
    const float* proj_b     = (const float*)d_in[5];
    const float* bias_table = (const float*)d_in[6];
    const int*   rel_index  = (const int*)d_in[7];
    float* out = (float*)d_out;

    const int B = in_sizes[0] / (NTOK * KDIM);   // 4096
    swin_window_attn_kernel<<<dim3(B), dim3(256), 0, stream>>>(
        x, attn_mask, qkv_w, qkv_b, proj_w, proj_b, bias_table, rel_index, out);
}

// Round 2
// 419.119 us; speedup vs baseline: 3.4772x; 3.4772x over previous
//
#include <hip/hip_runtime.h>
#include <math.h>

#define NTOK 49
#define KDIM 128
#define NH 4
#define HD 32
#define QK_SCALE 0.17677669529663687f  // 32^-0.5

typedef __attribute__((ext_vector_type(8))) short bf16x8;
typedef __attribute__((ext_vector_type(4))) float f32x4;
typedef __attribute__((ext_vector_type(8))) unsigned short us8;

static __device__ __forceinline__ unsigned short f2b(float f) {
    union { float f; unsigned int u; } v; v.f = f;
    return (unsigned short)((v.u + 0x7fffu + ((v.u >> 16) & 1u)) >> 16);  // RNE
}
static __device__ __forceinline__ float b2f(unsigned short h) {
    union { unsigned int u; float f; } v; v.u = ((unsigned int)h) << 16;
    return v.f;
}

// ---------------- workspace layout (bytes) ----------------
#define WS_WQ   0u            // qkv_w bf16   [384][128]  98304 B
#define WS_WP   98304u        // proj_w bf16  [128][128]  32768 B
#define WS_FB   131072u       // fused bias+mask fp32 [64][4][49][49] 2458624 B
#define WS_QKV  2589696u      // qkv bf16 [B*49][384] 154140672 B
#define WS_REQ  156730368ull

// ---------- K0a: convert weights to bf16 ----------
__global__ void k_cvt_weights(const float* __restrict__ qkv_w, const float* __restrict__ proj_w,
                              unsigned short* __restrict__ wq, unsigned short* __restrict__ wp) {
    int i = blockIdx.x * 256 + threadIdx.x;
    if (i < 3 * KDIM * KDIM) wq[i] = f2b(qkv_w[i]);
    if (i < KDIM * KDIM)     wp[i] = f2b(proj_w[i]);
}

// ---------- K0b: fb[wm][h][r][j] = bias_table[rel_index[r][j]][h] + attn_mask[wm][r][j] ----------
__global__ void k_fbias(const float* __restrict__ bias_table, const int* __restrict__ rel_index,
                        const float* __restrict__ attn_mask, float* __restrict__ fb) {
    int i = blockIdx.x * 256 + threadIdx.x;
    if (i >= 64 * NH * NTOK * NTOK) return;
    int j  = i % NTOK;
    int r  = (i / NTOK) % NTOK;
    int h  = (i / (NTOK * NTOK)) % NH;
    int wm = i / (NH * NTOK * NTOK);
    fb[i] = bias_table[rel_index[r * NTOK + j] * NH + h] + attn_mask[(wm * NTOK + r) * NTOK + j];
}

// ---------- K1: QKV GEMM  C[M=200704][384] = x[M][128] @ wq^T, bf16 MFMA ----------
// grid (1568, 3), 256 threads. LDS 68 KB -> 2 blocks/CU.
__launch_bounds__(256, 2)
__global__ void k_qkv_gemm(const float* __restrict__ x, const unsigned short* __restrict__ wq,
                           const float* __restrict__ qkv_b, unsigned short* __restrict__ qkv) {
    __shared__ unsigned short As[128 * 136];  // x tile bf16, stride 136 (272B: 2-way max on frag reads)
    __shared__ unsigned short Bs[128 * 136];  // weight tile bf16

    const int t  = threadIdx.x;
    const int mt = blockIdx.x, nt = blockIdx.y;
    const long m0 = (long)mt * 128;

    // stage A: 128x128 fp32 -> bf16 (coalesced float4)
    const float4* xg = (const float4*)(x + m0 * KDIM);
    #pragma unroll
    for (int i = 0; i < 16; ++i) {
        int idx = i * 256 + t;                 // float4 index in 128x128
        float4 v = xg[idx];
        int row = idx >> 5, col = (idx & 31) * 4;
        unsigned short* d = &As[row * 136 + col];
        d[0] = f2b(v.x); d[1] = f2b(v.y); d[2] = f2b(v.z); d[3] = f2b(v.w);
    }
    // stage B: bf16 us8 (coalesced 16B)
    const us8* wg = (const us8*)(wq + nt * 128 * KDIM);
    #pragma unroll
    for (int i = 0; i < 8; ++i) {
        int idx = i * 256 + t;                 // us8 index
        us8 v = wg[idx];
        int row = idx >> 4, col = (idx & 15) * 8;
        *(us8*)&Bs[row * 136 + col] = v;
    }
    __syncthreads();

    const int lane = t & 63, wv = t >> 6;
    const int wr = (wv >> 1) * 64, wc = (wv & 1) * 64;   // wave -> 64x64 quadrant
    const int fr = lane & 15, fg = lane >> 4;

    f32x4 acc[4][4];
    #pragma unroll
    for (int mi = 0; mi < 4; ++mi)
        #pragma unroll
        for (int ni = 0; ni < 4; ++ni) acc[mi][ni] = (f32x4){0.f, 0.f, 0.f, 0.f};

    #pragma unroll
    for (int ks = 0; ks < 4; ++ks) {
        bf16x8 af[4], bf[4];
        #pragma unroll
        for (int mi = 0; mi < 4; ++mi)
            af[mi] = *(const bf16x8*)&As[(wr + mi * 16 + fr) * 136 + ks * 32 + fg * 8];
        #pragma unroll
        for (int ni = 0; ni < 4; ++ni)
            bf[ni] = *(const bf16x8*)&Bs[(wc + ni * 16 + fr) * 136 + ks * 32 + fg * 8];
        #pragma unroll
        for (int mi = 0; mi < 4; ++mi)
            #pragma unroll
            for (int ni = 0; ni < 4; ++ni)
                acc[mi][ni] = __builtin_amdgcn_mfma_f32_16x16x32_bf16(af[mi], bf[ni], acc[mi][ni], 0, 0, 0);
    }
    __syncthreads();

    // epilogue: +bias, cvt bf16, relayout via As for coalesced global writes
    #pragma unroll
    for (int ni = 0; ni < 4; ++ni) {
        float bias = qkv_b[nt * 128 + wc + ni * 16 + fr];
        #pragma unroll
        for (int mi = 0; mi < 4; ++mi)
            #pragma unroll
            for (int reg = 0; reg < 4; ++reg)
                As[(wr + mi * 16 + fg * 4 + reg) * 136 + wc + ni * 16 + fr] = f2b(acc[mi][ni][reg] + bias);
    }
    __syncthreads();
    #pragma unroll
    for (int i = 0; i < 8; ++i) {
        int idx = i * 256 + t;
        int row = idx >> 4, col = (idx & 15) * 8;
        *(us8*)(qkv + (m0 + row) * 384 + nt * 128 + col) = *(const us8*)&As[row * 136 + col];
    }
}

// ---------- K2K3: per-window attention (fp32 VALU, P in regs) + proj (bf16 MFMA) ----------
// 256 threads = 4 waves = 4 heads. Arena 69152 B -> 2 blocks/CU.
#define S_K_OFF  0
#define S_V_OFF  25872        // 49*132*4
#define S_O_OFF  51744        // + 49*132*4 ; s_o ushort [64][136] = 17408 -> total 69152
#define WT_OFF   0            // proj weight tile [128][136] ushort = 34816 (reuses k/v region)
#define SOF_OFF  0            // fp32 relayout [64][132] = 33792 (reuses wt region)

__launch_bounds__(256, 2)
__global__ void k_attn_proj(const unsigned short* __restrict__ qkv,
                            const unsigned short* __restrict__ wp,
                            const float* __restrict__ proj_b,
                            const float* __restrict__ fb,
                            float* __restrict__ out) {
    __shared__ __align__(16) char arena[69152];
    float*          s_k  = (float*)(arena + S_K_OFF);            // [49][132] fp32
    float*          s_v  = (float*)(arena + S_V_OFF);            // [49][132] fp32
    unsigned short* s_o  = (unsigned short*)(arena + S_O_OFF);   // [64][136] bf16
    unsigned short* s_wt = (unsigned short*)(arena + WT_OFF);    // [128][136] bf16
    float*          s_of = (float*)(arena + SOF_OFF);            // [64][132] fp32

    const int b = blockIdx.x, t = threadIdx.x;
    const long gb = (long)b * NTOK;

    // stage K,V: bf16 -> fp32 LDS
    for (int i = t; i < NTOK * 16; i += 256) {
        int row = i >> 4, c = (i & 15) * 8;
        us8 kv = *(const us8*)(qkv + (gb + row) * 384 + 128 + c);
        us8 vv = *(const us8*)(qkv + (gb + row) * 384 + 256 + c);
        #pragma unroll
        for (int e = 0; e < 8; ++e) {
            s_k[row * 132 + c + e] = b2f(kv[e]);
            s_v[row * 132 + c + e] = b2f(vv[e]);
        }
    }
    __syncthreads();

    // ---- attention: wave = head, lane = query row, P in registers ----
    const int lane = t & 63, h = t >> 6;
    const int r = lane < NTOK ? lane : NTOK - 1;
    float q[HD];
    {
        const unsigned short* qg = qkv + (gb + r) * 384 + h * HD;
        #pragma unroll
        for (int d8 = 0; d8 < 4; ++d8) {
            us8 qv = *(const us8*)(qg + d8 * 8);
            #pragma unroll
            for (int e = 0; e < 8; ++e) q[d8 * 8 + e] = b2f(qv[e]) * QK_SCALE;
        }
    }
    const float* fbrow = fb + (((b & 63) * NH + h) * NTOK + r) * NTOK;

    float p[NTOK];
    float mx = -1e30f;
    #pragma unroll
    for (int j = 0; j < NTOK; ++j) {
        const float4* kr = (const float4*)&s_k[j * 132 + h * HD];
        float s = 0.f;
        #pragma unroll
        for (int d4 = 0; d4 < 8; ++d4) {
            float4 kv = kr[d4];
            s += q[d4*4+0]*kv.x + q[d4*4+1]*kv.y + q[d4*4+2]*kv.z + q[d4*4+3]*kv.w;
        }
        s += fbrow[j];
        p[j] = s;
        mx = fmaxf(mx, s);
    }
    float sum = 0.f;
    #pragma unroll
    for (int j = 0; j < NTOK; ++j) { float e = __expf(p[j] - mx); p[j] = e; sum += e; }
    const float rs = 1.0f / sum;

    float o[HD];
    #pragma unroll
    for (int d = 0; d < HD; ++d) o[d] = 0.f;
    #pragma unroll
    for (int j = 0; j < NTOK; ++j) {
        float pj = p[j] * rs;
        const float4* vr = (const float4*)&s_v[j * 132 + h * HD];
        #pragma unroll
        for (int d4 = 0; d4 < 8; ++d4) {
            float4 vv = vr[d4];
            o[d4*4+0] += pj*vv.x; o[d4*4+1] += pj*vv.y; o[d4*4+2] += pj*vv.z; o[d4*4+3] += pj*vv.w;
        }
    }
    if (lane < NTOK) {
        #pragma unroll
        for (int d = 0; d < HD; ++d) s_o[r * 136 + h * HD + d] = f2b(o[d]);
    }
    __syncthreads();   // k/v dead; s_o complete

    // ---- proj: stage weights (overlaps k/v region) ----
    #pragma unroll
    for (int i = 0; i < 8; ++i) {
        int idx = i * 256 + t;
        int row = idx >> 4, c = (idx & 15) * 8;
        *(us8*)&s_wt[row * 136 + c] = *(const us8*)(wp + row * KDIM + c);
    }
    __syncthreads();

    const int fr = lane & 15, fg = lane >> 4;
    f32x4 acc[4][2];
    #pragma unroll
    for (int mi = 0; mi < 4; ++mi) { acc[mi][0] = (f32x4){0,0,0,0}; acc[mi][1] = (f32x4){0,0,0,0}; }
    #pragma unroll
    for (int ks = 0; ks < 4; ++ks) {
        bf16x8 af[4], bfr[2];
        #pragma unroll
        for (int mi = 0; mi < 4; ++mi)
            af[mi] = *(const bf16x8*)&s_o[(mi * 16 + fr) * 136 + ks * 32 + fg * 8];
        #pragma unroll
        for (int ni = 0; ni < 2; ++ni)
            bfr[ni] = *(const bf16x8*)&s_wt[(h * 32 + ni * 16 + fr) * 136 + ks * 32 + fg * 8];
        #pragma unroll
        for (int mi = 0; mi < 4; ++mi)
            #pragma unroll
            for (int ni = 0; ni < 2; ++ni)
                acc[mi][ni] = __builtin_amdgcn_mfma_f32_16x16x32_bf16(af[mi], bfr[ni], acc[mi][ni], 0, 0, 0);
    }
    __syncthreads();   // s_wt reads done; reuse region for fp32 relayout

    #pragma unroll
    for (int ni = 0; ni < 2; ++ni) {
        float pb = proj_b[h * 32 + ni * 16 + fr];
        #pragma unroll
        for (int mi = 0; mi < 4; ++mi)
            #pragma unroll
            for (int reg = 0; reg < 4; ++reg)
                s_of[(mi * 16 + fg * 4 + reg) * 132 + h * 32 + ni * 16 + fr] = acc[mi][ni][reg] + pb;
    }
    __syncthreads();

    float* og = out + gb * KDIM;
    for (int i = t; i < NTOK * 32; i += 256) {
        int row = i >> 5, c4 = (i & 31) * 4;
        *(float4*)(og + row * KDIM + c4) = *(const float4*)&s_of[row * 132 + c4];
    }
}

// ---------- fallback (round-0 fused kernel) if ws too small ----------
__launch_bounds__(256, 1)
__global__ void swin_window_attn_fallback(
    const float* __restrict__ x, const float* __restrict__ attn_mask,
    const float* __restrict__ qkv_w, const float* __restrict__ qkv_b,
    const float* __restrict__ proj_w, const float* __restrict__ proj_b,
    const float* __restrict__ bias_table, const int* __restrict__ rel_index,
    float* __restrict__ out)
{
    __shared__ float xs[NTOK * 129];
    __shared__ float wt[64 * 129];
    __shared__ float s_qt[NH * HD * NTOK];
    __shared__ float s_k[NH * NTOK * HD];
    __shared__ float s_v[NH * NTOK * HD];
    __shared__ float s_ot[KDIM * NTOK];
    const int b = blockIdx.x, tid = threadIdx.x, wm = b & 63;
    const float* xg = x + (size_t)b * (NTOK * KDIM);
    for (int i = tid; i < (NTOK * KDIM) / 4; i += 256) {
        float4 t = reinterpret_cast<const float4*>(xg)[i];
        int idx = i * 4; int row = idx >> 7, col = idx & 127;
        float* dst = &xs[row * 129 + col];
        dst[0]=t.x; dst[1]=t.y; dst[2]=t.z; dst[3]=t.w;
    }
    __syncthreads();
    const int cx = tid & 15, ny = tid >> 4;
    const float* xrow[4];
    #pragma unroll
    for (int a = 0; a < 4; ++a) { int n = ny + 16*a; xrow[a] = &xs[(n < NTOK ? n : NTOK-1) * 129]; }
    for (int ct = 0; ct < 6; ++ct) {
        const float4* wg = reinterpret_cast<const float4*>(qkv_w + ct * (64 * KDIM));
        for (int i = tid; i < (64 * KDIM) / 4; i += 256) {
            float4 t = wg[i]; int idx = i * 4; int row = idx >> 7, col = idx & 127;
            float* dst = &wt[row * 129 + col];
            dst[0]=t.x; dst[1]=t.y; dst[2]=t.z; dst[3]=t.w;
        }
        __syncthreads();
        float acc[4][4];
        #pragma unroll
        for (int a=0;a<4;++a) for (int j=0;j<4;++j) acc[a][j]=0.f;
        for (int k = 0; k < KDIM; ++k) {
            float xr[4], wr[4];
            #pragma unroll
            for (int a=0;a<4;++a) xr[a]=xrow[a][k];
            #pragma unroll
            for (int j=0;j<4;++j) wr[j]=wt[(cx*4+j)*129+k];
            #pragma unroll
            for (int a=0;a<4;++a) for (int j=0;j<4;++j) acc[a][j]+=xr[a]*wr[j];
        }
        #pragma unroll
        for (int j = 0; j < 4; ++j) {
            const int c = ct*64 + cx*4 + j, which = c>>7, h = (c>>5)&3, d = c&31;
            const float bv = qkv_b[c];
            #pragma unroll
            for (int a = 0; a < 4; ++a) {
                int n = ny + 16*a;
                if (n < NTOK) {
                    float val = acc[a][j] + bv;
                    if (which==0)      s_qt[(h*HD+d)*NTOK+n] = val*QK_SCALE;
                    else if (which==1) s_k[(h*NTOK+n)*HD+d] = val;
                    else               s_v[(h*NTOK+n)*HD+d] = val;
                }
            }
        }
        __syncthreads();
    }
    {
        const int h = tid >> 6, lane = tid & 63;
        const int r = lane < NTOK ? lane : NTOK-1;
        float qreg[HD];
        #pragma unroll
        for (int d=0;d<HD;++d) qreg[d]=s_qt[(h*HD+d)*NTOK+r];
        const int* ri = rel_index + r*NTOK;
        const float* mrow = attn_mask + ((size_t)wm*NTOK + r)*NTOK;
        float p[NTOK]; float mxv = -1e30f;
        #pragma unroll
        for (int j=0;j<NTOK;++j) {
            const float* krow = &s_k[(h*NTOK+j)*HD];
            float s=0.f;
            #pragma unroll
            for (int d=0;d<HD;++d) s += qreg[d]*krow[d];
            s += bias_table[ri[j]*NH+h] + mrow[j];
            p[j]=s; mxv=fmaxf(mxv,s);
        }
        float sum=0.f;
        #pragma unroll
        for (int j=0;j<NTOK;++j){ float e=__expf(p[j]-mxv); p[j]=e; sum+=e; }
        const float rsv = 1.0f/sum;
        float o[HD];
        #pragma unroll
        for (int d=0;d<HD;++d) o[d]=0.f;
        #pragma unroll
        for (int j=0;j<NTOK;++j){
            float pj=p[j]*rsv;
            const float* vrow=&s_v[(h*NTOK+j)*HD];
            #pragma unroll
            for (int d=0;d<HD;++d) o[d]+=pj*vrow[d];
        }
        if (lane < NTOK) {
            #pragma unroll
            for (int d=0;d<HD;++d) s_ot[(h*HD+d)*NTOK+r]=o[d];
        }
    }
    __syncthreads();
    float* outg = out + (size_t)b * (NTOK * KDIM);
    for (int ct = 0; ct < 2; ++ct) {
        const float4* wg = reinterpret_cast<const float4*>(proj_w + ct * (64 * KDIM));
        for (int i = tid; i < (64 * KDIM) / 4; i += 256) {
            float4 t = wg[i]; int idx = i * 4; int row = idx >> 7, col = idx & 127;
            float* dst = &wt[row * 129 + col];
            dst[0]=t.x; dst[1]=t.y; dst[2]=t.z; dst[3]=t.w;
        }
        __syncthreads();
        float acc[4][4];
        #pragma unroll
        for (int a=0;a<4;++a) for (int j=0;j<4;++j) acc[a][j]=0.f;
        int nclamp[4];
        #pragma unroll
        for (int a=0;a<4;++a){ int n=ny+16*a; nclamp[a]=(n<NTOK?n:NTOK-1); }
        for (int k = 0; k < KDIM; ++k) {
            float xr[4], wr[4];
            #pragma unroll
            for (int a=0;a<4;++a) xr[a]=s_ot[k*NTOK+nclamp[a]];
            #pragma unroll
            for (int j=0;j<4;++j) wr[j]=wt[(cx*4+j)*129+k];
            #pragma unroll
            for (int a=0;a<4;++a) for (int j=0;j<4;++j) acc[a][j]+=xr[a]*wr[j];
        }
        const int c0 = ct*64 + cx*4;
        float pb[4];
        #pragma unroll
        for (int j=0;j<4;++j) pb[j]=proj_b[c0+j];
        #pragma unroll
        for (int a = 0; a < 4; ++a) {
            int n = ny + 16*a;
            if (n < NTOK) {
                float4 res; res.x=acc[a][0]+pb[0]; res.y=acc[a][1]+pb[1];
                res.z=acc[a][2]+pb[2]; res.w=acc[a][3]+pb[3];
                *reinterpret_cast<float4*>(&outg[n*KDIM+c0]) = res;
            }
        }
        __syncthreads();
    }
}

extern "C" void kernel_launch(void* const* d_in, const int* in_sizes, int n_in,
                              void* d_out, int out_size, void* d_ws, size_t ws_size,
                              hipStream_t stream) {
    const float* x          = (const float*)d_in[0];
    const float* attn_mask  = (const float*)d_in[1];
    const float* qkv_w      = (const float*)d_in[2];
    const float* qkv_b      = (const float*)d_in[3];
    const float* proj_w     = (const float*)d_in[4];
    const float* proj_b     = (const float*)d_in[5];
    const float* bias_table = (const float*)d_in[6];
    const int*   rel_index  = (const int*)d_in[7];
    float* out = (float*)d_out;
    const int B = in_sizes[0] / (NTOK * KDIM);   // 4096

    if (ws_size >= WS_REQ && (B * NTOK) % 128 == 0) {
        unsigned short* wq  = (unsigned short*)((char*)d_ws + WS_WQ);
        unsigned short* wpp = (unsigned short*)((char*)d_ws + WS_WP);
        float*          fbp = (float*)((char*)d_ws + WS_FB);
        unsigned short* qkvp = (unsigned short*)((char*)d_ws + WS_QKV);

        k_cvt_weights<<<192, 256, 0, stream>>>(qkv_w, proj_w, wq, wpp);
        k_fbias<<<2401, 256, 0, stream>>>(bias_table, rel_index, attn_mask, fbp);
        k_qkv_gemm<<<dim3((B * NTOK) / 128, 3), 256, 0, stream>>>(x, wq, qkv_b, qkvp);
        k_attn_proj<<<B, 256, 0, stream>>>(qkvp, wpp, proj_b, fbp, out);
    } else {
        swin_window_attn_fallback<<<B, 256, 0, stream>>>(
            x, attn_mask, qkv_w, qkv_b, proj_w, proj_b, bias_table, rel_index, out);
    }
}

// Round 3
// 328.980 us; speedup vs baseline: 4.4299x; 1.2740x over previous
//
#include <hip/hip_runtime.h>
#include <math.h>

#define NTOK 49
#define KDIM 128
#define NH 4
#define HD 32
#define QK_SCALE 0.17677669529663687f  // 32^-0.5

typedef __attribute__((ext_vector_type(8))) short bf16x8;
typedef __attribute__((ext_vector_type(4))) float f32x4;
typedef __attribute__((ext_vector_type(8))) unsigned short us8;

static __device__ __forceinline__ unsigned short f2b(float f) {
    union { float f; unsigned int u; } v; v.f = f;
    return (unsigned short)((v.u + 0x7fffu + ((v.u >> 16) & 1u)) >> 16);  // RNE
}

// ---------------- workspace layout (bytes) ----------------
#define WS_WQ   0u            // qkv_w bf16 [384][128], Q rows pre-scaled   98304 B
#define WS_WP   98304u        // proj_w bf16 [128][128]                     32768 B
#define WS_FB   131072u       // fused bias+mask fp32 [64][4][49][49]     2458624 B
#define WS_REQ  2589696ull

// ---------- K0a: weights -> bf16 (fold QK_SCALE into Q rows of qkv_w) ----------
__global__ void k_cvt_weights(const float* __restrict__ qkv_w, const float* __restrict__ proj_w,
                              unsigned short* __restrict__ wq, unsigned short* __restrict__ wp) {
    int i = blockIdx.x * 256 + threadIdx.x;
    if (i < 3 * KDIM * KDIM) {
        float v = qkv_w[i];
        if (i < KDIM * KDIM) v *= QK_SCALE;   // Q rows
        wq[i] = f2b(v);
    }
    if (i < KDIM * KDIM) wp[i] = f2b(proj_w[i]);
}

// ---------- K0b: fb[wm][h][r][j] = bias_table[rel_index[r][j]][h] + attn_mask[wm][r][j] ----------
__global__ void k_fbias(const float* __restrict__ bias_table, const int* __restrict__ rel_index,
                        const float* __restrict__ attn_mask, float* __restrict__ fb) {
    int i = blockIdx.x * 256 + threadIdx.x;
    if (i >= 64 * NH * NTOK * NTOK) return;
    int j  = i % NTOK;
    int r  = (i / NTOK) % NTOK;
    int h  = (i / (NTOK * NTOK)) % NH;
    int wm = i / (NH * NTOK * NTOK);
    fb[i] = bias_table[rel_index[r * NTOK + j] * NH + h] + attn_mask[(wm * NTOK + r) * NTOK + j];
}

// ---------------- fused per-window kernel ----------------
// 256 threads = 4 waves. Phases: x-stage -> qkv MFMA (B-frags from global) ->
// S MFMA + in-reg softmax -> P to LDS -> PV MFMA -> s_o -> proj MFMA -> out.
// LDS arena 76800 B -> 2 blocks/CU.
//   [0,17408)      s_x [64][136] bf16       (later s_o [64][136])
//   [17408,37888)  s_q [4][64][40] bf16     (later s_p [4][64][72], ends 54272)
//   [37888,58368)  s_k [4][64][40] bf16
//   [58368,76800)  vt  [4][32][72] bf16  (V transposed, free via D-layout scatter)
__launch_bounds__(256, 2)
__global__ void k_fused(const float* __restrict__ x,
                        const unsigned short* __restrict__ wq,
                        const unsigned short* __restrict__ wp,
                        const float* __restrict__ qkv_b,
                        const float* __restrict__ proj_b,
                        const float* __restrict__ fb,
                        float* __restrict__ out) {
    __shared__ __align__(16) char arena[76800];
    unsigned short* s_x = (unsigned short*)arena;              // [64][136]
    unsigned short* s_o = (unsigned short*)arena;              // [64][136]
    unsigned short* s_q = (unsigned short*)(arena + 17408);    // [4][64][40]
    unsigned short* s_k = (unsigned short*)(arena + 37888);    // [4][64][40]
    unsigned short* s_p = (unsigned short*)(arena + 17408);    // [4][64][72]
    unsigned short* vt  = (unsigned short*)(arena + 58368);    // [4][32][72]

    const int b = blockIdx.x, t = threadIdx.x;
    const int lane = t & 63, wid = t >> 6;
    const int fr = lane & 15, fg = lane >> 4;
    const int gb = b * NTOK;

    // ---- phase 0: stage x -> bf16 LDS; zero pad rows 49..63 ----
    {
        const float4* xg = (const float4*)(x + (size_t)gb * KDIM);
        for (int i = t; i < NTOK * 32; i += 256) {           // 1568 float4
            float4 v = xg[i];
            int row = i >> 5, col = (i & 31) * 4;
            unsigned short* d = &s_x[row * 136 + col];
            d[0] = f2b(v.x); d[1] = f2b(v.y); d[2] = f2b(v.z); d[3] = f2b(v.w);
        }
        if (t < 255) {                                        // 15 rows x 136 = 255 us8
            int row = 49 + t / 17, c8 = (t % 17) * 8;
            *(us8*)&s_x[row * 136 + c8] = (us8){0,0,0,0,0,0,0,0};
        }
    }
    __syncthreads();   // B0

    // ---- phase 1: qkv GEMM. wave wid handles nt = wid*6 .. wid*6+5 (c = nt*16..) ----
    {
        bf16x8 ax[4][4];
        #pragma unroll
        for (int mt = 0; mt < 4; ++mt)
            #pragma unroll
            for (int ks = 0; ks < 4; ++ks)
                ax[mt][ks] = *(const bf16x8*)&s_x[(mt * 16 + fr) * 136 + ks * 32 + fg * 8];

        #pragma unroll
        for (int i = 0; i < 6; ++i) {
            const int nt = wid * 6 + i;
            const int which = nt >> 3;            // 0=Q,1=K,2=V (uniform per nt)
            const int head = (nt >> 1) & 3;
            const int dbase = (nt & 1) * 16;

            bf16x8 bw[4];
            #pragma unroll
            for (int ks = 0; ks < 4; ++ks)
                bw[ks] = *(const bf16x8*)(wq + (nt * 16 + fr) * KDIM + ks * 32 + fg * 8);

            f32x4 acc[4];
            #pragma unroll
            for (int mt = 0; mt < 4; ++mt) acc[mt] = (f32x4){0.f, 0.f, 0.f, 0.f};
            #pragma unroll
            for (int ks = 0; ks < 4; ++ks)
                #pragma unroll
                for (int mt = 0; mt < 4; ++mt)
                    acc[mt] = __builtin_amdgcn_mfma_f32_16x16x32_bf16(ax[mt][ks], bw[ks], acc[mt], 0, 0, 0);

            float bias = qkv_b[nt * 16 + fr] * (which == 0 ? QK_SCALE : 1.f);

            if (which == 2) {
                // V: D rows = 4 consecutive toks at fixed d -> packed b64 into vt[head][d][tok]
                unsigned short* base = vt + head * (32 * 72) + (dbase + fr) * 72;
                #pragma unroll
                for (int mt = 0; mt < 4; ++mt) {
                    ushort4 pk;
                    pk.x = f2b(acc[mt][0] + bias); pk.y = f2b(acc[mt][1] + bias);
                    pk.z = f2b(acc[mt][2] + bias); pk.w = f2b(acc[mt][3] + bias);
                    *(ushort4*)&base[mt * 16 + fg * 4] = pk;
                }
            } else {
                unsigned short* base = (which == 0 ? s_q : s_k) + head * (64 * 40) + dbase + fr;
                #pragma unroll
                for (int mt = 0; mt < 4; ++mt)
                    #pragma unroll
                    for (int reg = 0; reg < 4; ++reg)
                        base[(mt * 16 + fg * 4 + reg) * 40] = f2b(acc[mt][reg] + bias);
            }
        }
    }
    __syncthreads();   // B1: s_q/s_k/vt complete

    // ---- phase 2: S = Q K^T (wave = head), softmax in registers ----
    f32x4 sacc[4][4];   // [mt(q)][ct(k)]
    {
        const unsigned short* q_h = s_q + wid * (64 * 40);
        const unsigned short* k_h = s_k + wid * (64 * 40);
        bf16x8 aq[4];
        #pragma unroll
        for (int mt = 0; mt < 4; ++mt)
            aq[mt] = *(const bf16x8*)&q_h[(mt * 16 + fr) * 40 + fg * 8];
        #pragma unroll
        for (int ct = 0; ct < 4; ++ct) {
            bf16x8 bk = *(const bf16x8*)&k_h[(ct * 16 + fr) * 40 + fg * 8];
            #pragma unroll
            for (int mt = 0; mt < 4; ++mt)
                sacc[mt][ct] = __builtin_amdgcn_mfma_f32_16x16x32_bf16(aq[mt], bk, (f32x4){0.f,0.f,0.f,0.f}, 0, 0, 0);
        }

        const float* fbh = fb + (((b & 63) * NH + wid) * NTOK) * NTOK;
        #pragma unroll
        for (int mt = 0; mt < 4; ++mt) {
            #pragma unroll
            for (int reg = 0; reg < 4; ++reg) {
                const int q = mt * 16 + fg * 4 + reg;
                float v[4];
                #pragma unroll
                for (int ct = 0; ct < 4; ++ct) {
                    const int k = ct * 16 + fr;
                    float fbv = (q < NTOK && k < NTOK) ? fbh[q * NTOK + k] : 0.f;
                    float s = sacc[mt][ct][reg] + fbv;
                    v[ct] = (k < NTOK) ? s : -1e30f;
                }
                float m = fmaxf(fmaxf(v[0], v[1]), fmaxf(v[2], v[3]));
                #pragma unroll
                for (int sft = 1; sft < 16; sft <<= 1) m = fmaxf(m, __shfl_xor(m, sft));
                float sum = 0.f;
                #pragma unroll
                for (int ct = 0; ct < 4; ++ct) { float e = __expf(v[ct] - m); v[ct] = e; sum += e; }
                #pragma unroll
                for (int sft = 1; sft < 16; sft <<= 1) sum += __shfl_xor(sum, sft);
                const float r = 1.f / sum;
                #pragma unroll
                for (int ct = 0; ct < 4; ++ct) sacc[mt][ct][reg] = v[ct] * r;
            }
        }
    }
    __syncthreads();   // B2: all s_q/s_k reads done before P overlays them

    // ---- phase 3: P -> LDS (own head), then PV ----
    f32x4 oacc[4][2];   // [mt(q)][ni(d)]
    {
        unsigned short* p_h = s_p + wid * (64 * 72);
        #pragma unroll
        for (int mt = 0; mt < 4; ++mt)
            #pragma unroll
            for (int ct = 0; ct < 4; ++ct)
                #pragma unroll
                for (int reg = 0; reg < 4; ++reg)
                    p_h[(mt * 16 + fg * 4 + reg) * 72 + ct * 16 + fr] = f2b(sacc[mt][ct][reg]);

        const unsigned short* vt_h = vt + wid * (32 * 72);
        bf16x8 bv[2][2];
        #pragma unroll
        for (int ni = 0; ni < 2; ++ni)
            #pragma unroll
            for (int ks = 0; ks < 2; ++ks)
                bv[ni][ks] = *(const bf16x8*)&vt_h[(ni * 16 + fr) * 72 + ks * 32 + fg * 8];

        #pragma unroll
        for (int mt = 0; mt < 4; ++mt) {
            oacc[mt][0] = (f32x4){0.f,0.f,0.f,0.f};
            oacc[mt][1] = (f32x4){0.f,0.f,0.f,0.f};
            #pragma unroll
            for (int ks = 0; ks < 2; ++ks) {
                bf16x8 ap = *(const bf16x8*)&p_h[(mt * 16 + fr) * 72 + ks * 32 + fg * 8];
                #pragma unroll
                for (int ni = 0; ni < 2; ++ni)
                    oacc[mt][ni] = __builtin_amdgcn_mfma_f32_16x16x32_bf16(ap, bv[ni][ks], oacc[mt][ni], 0, 0, 0);
            }
        }
        // O -> s_o[tok][C]  (C = wid*32 + ni*16 + fr); overlays dead s_x
        #pragma unroll
        for (int mt = 0; mt < 4; ++mt)
            #pragma unroll
            for (int ni = 0; ni < 2; ++ni)
                #pragma unroll
                for (int reg = 0; reg < 4; ++reg)
                    s_o[(mt * 16 + fg * 4 + reg) * 136 + wid * 32 + ni * 16 + fr] = f2b(oacc[mt][ni][reg]);
    }
    __syncthreads();   // B3: s_o complete

    // ---- phase 4: out = o @ proj_w^T + proj_b (B-frags from global wp) ----
    {
        bf16x8 ao[4][4];
        #pragma unroll
        for (int mt = 0; mt < 4; ++mt)
            #pragma unroll
            for (int ks = 0; ks < 4; ++ks)
                ao[mt][ks] = *(const bf16x8*)&s_o[(mt * 16 + fr) * 136 + ks * 32 + fg * 8];

        #pragma unroll
        for (int i = 0; i < 2; ++i) {
            const int nt = wid * 2 + i;
            bf16x8 bw[4];
            #pragma unroll
            for (int ks = 0; ks < 4; ++ks)
                bw[ks] = *(const bf16x8*)(wp + (nt * 16 + fr) * KDIM + ks * 32 + fg * 8);
            f32x4 acc[4];
            #pragma unroll
            for (int mt = 0; mt < 4; ++mt) acc[mt] = (f32x4){0.f,0.f,0.f,0.f};
            #pragma unroll
            for (int ks = 0; ks < 4; ++ks)
                #pragma unroll
                for (int mt = 0; mt < 4; ++mt)
                    acc[mt] = __builtin_amdgcn_mfma_f32_16x16x32_bf16(ao[mt][ks], bw[ks], acc[mt], 0, 0, 0);
            const float pb = proj_b[nt * 16 + fr];
            #pragma unroll
            for (int mt = 0; mt < 4; ++mt)
                #pragma unroll
                for (int reg = 0; reg < 4; ++reg) {
                    const int tok = mt * 16 + fg * 4 + reg;
                    if (tok < NTOK)
                        out[(size_t)(gb + tok) * KDIM + nt * 16 + fr] = acc[mt][reg] + pb;
                }
        }
    }
}

// ---------- fallback (round-0 fused fp32 kernel) if ws too small ----------
__launch_bounds__(256, 1)
__global__ void swin_window_attn_fallback(
    const float* __restrict__ x, const float* __restrict__ attn_mask,
    const float* __restrict__ qkv_w, const float* __restrict__ qkv_b,
    const float* __restrict__ proj_w, const float* __restrict__ proj_b,
    const float* __restrict__ bias_table, const int* __restrict__ rel_index,
    float* __restrict__ out)
{
    __shared__ float xs[NTOK * 129];
    __shared__ float wt[64 * 129];
    __shared__ float s_qt[NH * HD * NTOK];
    __shared__ float s_k[NH * NTOK * HD];
    __shared__ float s_v[NH * NTOK * HD];
    __shared__ float s_ot[KDIM * NTOK];
    const int b = blockIdx.x, tid = threadIdx.x, wm = b & 63;
    const float* xg = x + (size_t)b * (NTOK * KDIM);
    for (int i = tid; i < (NTOK * KDIM) / 4; i += 256) {
        float4 t = reinterpret_cast<const float4*>(xg)[i];
        int idx = i * 4; int row = idx >> 7, col = idx & 127;
        float* dst = &xs[row * 129 + col];
        dst[0]=t.x; dst[1]=t.y; dst[2]=t.z; dst[3]=t.w;
    }
    __syncthreads();
    const int cx = tid & 15, ny = tid >> 4;
    const float* xrow[4];
    #pragma unroll
    for (int a = 0; a < 4; ++a) { int n = ny + 16*a; xrow[a] = &xs[(n < NTOK ? n : NTOK-1) * 129]; }
    for (int ct = 0; ct < 6; ++ct) {
        const float4* wg = reinterpret_cast<const float4*>(qkv_w + ct * (64 * KDIM));
        for (int i = tid; i < (64 * KDIM) / 4; i += 256) {
            float4 t = wg[i]; int idx = i * 4; int row = idx >> 7, col = idx & 127;
            float* dst = &wt[row * 129 + col];
            dst[0]=t.x; dst[1]=t.y; dst[2]=t.z; dst[3]=t.w;
        }
        __syncthreads();
        float acc[4][4];
        #pragma unroll
        for (int a=0;a<4;++a) for (int j=0;j<4;++j) acc[a][j]=0.f;
        for (int k = 0; k < KDIM; ++k) {
            float xr[4], wr[4];
            #pragma unroll
            for (int a=0;a<4;++a) xr[a]=xrow[a][k];
            #pragma unroll
            for (int j=0;j<4;++j) wr[j]=wt[(cx*4+j)*129+k];
            #pragma unroll
            for (int a=0;a<4;++a) for (int j=0;j<4;++j) acc[a][j]+=xr[a]*wr[j];
        }
        #pragma unroll
        for (int j = 0; j < 4; ++j) {
            const int c = ct*64 + cx*4 + j, which = c>>7, h = (c>>5)&3, d = c&31;
            const float bv = qkv_b[c];
            #pragma unroll
            for (int a = 0; a < 4; ++a) {
                int n = ny + 16*a;
                if (n < NTOK) {
                    float val = acc[a][j] + bv;
                    if (which==0)      s_qt[(h*HD+d)*NTOK+n] = val*QK_SCALE;
                    else if (which==1) s_k[(h*NTOK+n)*HD+d] = val;
                    else               s_v[(h*NTOK+n)*HD+d] = val;
                }
            }
        }
        __syncthreads();
    }
    {
        const int h = tid >> 6, lane = tid & 63;
        const int r = lane < NTOK ? lane : NTOK-1;
        float qreg[HD];
        #pragma unroll
        for (int d=0;d<HD;++d) qreg[d]=s_qt[(h*HD+d)*NTOK+r];
        const int* ri = rel_index + r*NTOK;
        const float* mrow = attn_mask + ((size_t)wm*NTOK + r)*NTOK;
        float p[NTOK]; float mxv = -1e30f;
        #pragma unroll
        for (int j=0;j<NTOK;++j) {
            const float* krow = &s_k[(h*NTOK+j)*HD];
            float s=0.f;
            #pragma unroll
            for (int d=0;d<HD;++d) s += qreg[d]*krow[d];
            s += bias_table[ri[j]*NH+h] + mrow[j];
            p[j]=s; mxv=fmaxf(mxv,s);
        }
        float sum=0.f;
        #pragma unroll
        for (int j=0;j<NTOK;++j){ float e=__expf(p[j]-mxv); p[j]=e; sum+=e; }
        const float rsv = 1.0f/sum;
        float o[HD];
        #pragma unroll
        for (int d=0;d<HD;++d) o[d]=0.f;
        #pragma unroll
        for (int j=0;j<NTOK;++j){
            float pj=p[j]*rsv;
            const float* vrow=&s_v[(h*NTOK+j)*HD];
            #pragma unroll
            for (int d=0;d<HD;++d) o[d]+=pj*vrow[d];
        }
        if (lane < NTOK) {
            #pragma unroll
            for (int d=0;d<HD;++d) s_ot[(h*HD+d)*NTOK+r]=o[d];
        }
    }
    __syncthreads();
    float* outg = out + (size_t)b * (NTOK * KDIM);
    for (int ct = 0; ct < 2; ++ct) {
        const float4* wg = reinterpret_cast<const float4*>(proj_w + ct * (64 * KDIM));
        for (int i = tid; i < (64 * KDIM) / 4; i += 256) {
            float4 t = wg[i]; int idx = i * 4; int row = idx >> 7, col = idx & 127;
            float* dst = &wt[row * 129 + col];
            dst[0]=t.x; dst[1]=t.y; dst[2]=t.z; dst[3]=t.w;
        }
        __syncthreads();
        float acc[4][4];
        #pragma unroll
        for (int a=0;a<4;++a) for (int j=0;j<4;++j) acc[a][j]=0.f;
        int nclamp[4];
        #pragma unroll
        for (int a=0;a<4;++a){ int n=ny+16*a; nclamp[a]=(n<NTOK?n:NTOK-1); }
        for (int k = 0; k < KDIM; ++k) {
            float xr[4], wr[4];
            #pragma unroll
            for (int a=0;a<4;++a) xr[a]=s_ot[k*NTOK+nclamp[a]];
            #pragma unroll
            for (int j=0;j<4;++j) wr[j]=wt[(cx*4+j)*129+k];
            #pragma unroll
            for (int a=0;a<4;++a) for (int j=0;j<4;++j) acc[a][j]+=xr[a]*wr[j];
        }
        const int c0 = ct*64 + cx*4;
        float pb[4];
        #pragma unroll
        for (int j=0;j<4;++j) pb[j]=proj_b[c0+j];
        #pragma unroll
        for (int a = 0; a < 4; ++a) {
            int n = ny + 16*a;
            if (n < NTOK) {
                float4 res; res.x=acc[a][0]+pb[0]; res.y=acc[a][1]+pb[1];
                res.z=acc[a][2]+pb[2]; res.w=acc[a][3]+pb[3];
                *reinterpret_cast<float4*>(&outg[n*KDIM+c0]) = res;
            }
        }
        __syncthreads();
    }
}

extern "C" void kernel_launch(void* const* d_in, const int* in_sizes, int n_in,
                              void* d_out, int out_size, void* d_ws, size_t ws_size,
                              hipStream_t stream) {
    const float* x          = (const float*)d_in[0];
    const float* attn_mask  = (const float*)d_in[1];
    const float* qkv_w      = (const float*)d_in[2];
    const float* qkv_b      = (const float*)d_in[3];
    const float* proj_w     = (const float*)d_in[4];
    const float* proj_b     = (const float*)d_in[5];
    const float* bias_table = (const float*)d_in[6];
    const int*   rel_index  = (const int*)d_in[7];
    float* out = (float*)d_out;
    const int B = in_sizes[0] / (NTOK * KDIM);   // 4096

    if (ws_size >= WS_REQ) {
        unsigned short* wq  = (unsigned short*)((char*)d_ws + WS_WQ);
        unsigned short* wpp = (unsigned short*)((char*)d_ws + WS_WP);
        float*          fbp = (float*)((char*)d_ws + WS_FB);

        k_cvt_weights<<<192, 256, 0, stream>>>(qkv_w, proj_w, wq, wpp);
        k_fbias<<<2401, 256, 0, stream>>>(bias_table, rel_index, attn_mask, fbp);
        k_fused<<<B, 256, 0, stream>>>(x, wq, wpp, qkv_b, proj_b, fbp, out);
    } else {
        swin_window_attn_fallback<<<B, 256, 0, stream>>>(
            x, attn_mask, qkv_w, qkv_b, proj_w, proj_b, bias_table, rel_index, out);
    }
}